// Round 1
// baseline (52331.702 us; speedup 1.0000x reference)
//
#include <hip/hip_runtime.h>
#include <hip/hip_bf16.h>
#include <math.h>

// ---- problem constants ----
#define B_    64
#define NTOK  197
#define NPATCH 196
#define D768  768
#define NL    12
#define NH    12
#define DH64  64
#define MFF   3072
#define NCLS  1000
#define ROWS  (B_ * NTOK)      // 12608
#define PROWS (B_ * NPATCH)    // 12544

// ---------------- block-wide mean/rstd over 768 elems (256 threads) ----------------
__device__ __forceinline__ void block_mean_rstd(float s, float sq, float& mean, float& rstd) {
#pragma unroll
  for (int off = 32; off; off >>= 1) { s += __shfl_xor(s, off); sq += __shfl_xor(sq, off); }
  __shared__ float ss[4], ssq[4];
  int w = threadIdx.x >> 6;
  if ((threadIdx.x & 63) == 0) { ss[w] = s; ssq[w] = sq; }
  __syncthreads();
  s  = ss[0] + ss[1] + ss[2] + ss[3];
  sq = ssq[0] + ssq[1] + ssq[2] + ssq[3];
  mean = s * (1.0f / 768.0f);
  float var = sq * (1.0f / 768.0f) - mean * mean;
  rstd = rsqrtf(var + 1e-5f);
}

// ---------------- LN over rows of 768; input row stride configurable ----------------
__global__ __launch_bounds__(256) void ln_rows(const float* __restrict__ in, long in_stride,
                                               const float* __restrict__ g,
                                               const float* __restrict__ bta,
                                               float* __restrict__ out) {
  const float* xr = in + (size_t)blockIdx.x * in_stride;
  int t = threadIdx.x;
  float v0 = xr[t], v1 = xr[t + 256], v2 = xr[t + 512];
  float mean, rstd;
  block_mean_rstd(v0 + v1 + v2, v0 * v0 + v1 * v1 + v2 * v2, mean, rstd);
  float* o = out + (size_t)blockIdx.x * 768;
  o[t]       = (v0 - mean) * rstd * g[t]       + bta[t];
  o[t + 256] = (v1 - mean) * rstd * g[t + 256] + bta[t + 256];
  o[t + 512] = (v2 - mean) * rstd * g[t + 512] + bta[t + 512];
}

// ---------------- patch extraction + LN1 ----------------
__global__ __launch_bounds__(256) void patch_ln1(const float* __restrict__ img,
                                                 const float* __restrict__ g,
                                                 const float* __restrict__ bta,
                                                 float* __restrict__ xp) {
  int pidx = blockIdx.x;                 // b*196 + ph*14 + pw
  int b = pidx / NPATCH, hw = pidx % NPATCH;
  int ph = hw / 14, pw = hw % 14;
  int t = threadIdx.x;
  float v[3];
#pragma unroll
  for (int u = 0; u < 3; ++u) {
    int k = t + u * 256;                  // feature index (p1*16+p2)*3 + c
    int c = k % 3, p2 = (k / 3) & 15, p1 = k / 48;
    v[u] = img[(((size_t)b * 3 + c) * 224 + ph * 16 + p1) * 224 + pw * 16 + p2];
  }
  float mean, rstd;
  block_mean_rstd(v[0] + v[1] + v[2], v[0] * v[0] + v[1] * v[1] + v[2] * v[2], mean, rstd);
  float* o = xp + (size_t)pidx * 768;
#pragma unroll
  for (int u = 0; u < 3; ++u) { int k = t + u * 256; o[k] = (v[u] - mean) * rstd * g[k] + bta[k]; }
}

// ---------------- LN2 + pos_emb, scatter into x at token 1+i ----------------
__global__ __launch_bounds__(256) void ln2_pos(const float* __restrict__ xe,
                                               const float* __restrict__ g,
                                               const float* __restrict__ bta,
                                               const float* __restrict__ pos,
                                               float* __restrict__ x) {
  int pidx = blockIdx.x;
  int b = pidx / NPATCH, i = pidx % NPATCH;
  const float* xr = xe + (size_t)pidx * 768;
  int t = threadIdx.x;
  float v0 = xr[t], v1 = xr[t + 256], v2 = xr[t + 512];
  float mean, rstd;
  block_mean_rstd(v0 + v1 + v2, v0 * v0 + v1 * v1 + v2 * v2, mean, rstd);
  const float* p = pos + (size_t)(1 + i) * 768;
  float* o = x + ((size_t)b * NTOK + 1 + i) * 768;
  o[t]       = (v0 - mean) * rstd * g[t]       + bta[t]       + p[t];
  o[t + 256] = (v1 - mean) * rstd * g[t + 256] + bta[t + 256] + p[t + 256];
  o[t + 512] = (v2 - mean) * rstd * g[t + 512] + bta[t + 512] + p[t + 512];
}

// ---------------- cls token + pos_emb[0] ----------------
__global__ __launch_bounds__(256) void cls_init(const float* __restrict__ cls_tok,
                                                const float* __restrict__ pos,
                                                float* __restrict__ x) {
  int b = blockIdx.x, t = threadIdx.x;
  float* o = x + (size_t)b * NTOK * 768;
#pragma unroll
  for (int u = 0; u < 3; ++u) { int k = t + u * 256; o[k] = cls_tok[k] + pos[k]; }
}

// ---------------- fp32 SGEMM, 128x128 tile, BK=8, 256 thr, 8x8 per thread ----------------
// C[r,c] = epilogue(A[r,:]*B[:,c] + bias[c]) + resid[r,c]
// ep: 0 = none, 1 = exact GELU
__global__ __launch_bounds__(256) void gemm128(const float* __restrict__ A,
                                               const float* __restrict__ Bm,
                                               const float* __restrict__ bias,
                                               const float* __restrict__ resid,
                                               float* __restrict__ C,
                                               int M, int N, int K, int ep) {
  __shared__ float As[8][128];
  __shared__ float Bs[8][128];
  int tid = threadIdx.x;
  int tx = tid & 15, ty = tid >> 4;
  int row0 = blockIdx.y * 128, col0 = blockIdx.x * 128;
  float acc[8][8] = {};

  int am = tid >> 1;            // 0..127 : A row within tile
  int ak = (tid & 1) * 4;       // 0 or 4 : A k-offset
  int bk = tid >> 5;            // 0..7   : B k row
  int bn = (tid & 31) * 4;      // 0..124 : B col offset

  for (int k0 = 0; k0 < K; k0 += 8) {
    float4 av;
    int gr = row0 + am;
    if (gr < M) av = *(const float4*)(A + (size_t)gr * K + k0 + ak);
    else        av = make_float4(0.f, 0.f, 0.f, 0.f);
    As[ak + 0][am] = av.x; As[ak + 1][am] = av.y;
    As[ak + 2][am] = av.z; As[ak + 3][am] = av.w;

    float4 bv;
    if (col0 + 128 <= N) {
      bv = *(const float4*)(Bm + (size_t)(k0 + bk) * N + col0 + bn);
    } else {
      const float* bp = Bm + (size_t)(k0 + bk) * N;
      int c = col0 + bn;
      bv.x = (c + 0 < N) ? bp[c + 0] : 0.f;
      bv.y = (c + 1 < N) ? bp[c + 1] : 0.f;
      bv.z = (c + 2 < N) ? bp[c + 2] : 0.f;
      bv.w = (c + 3 < N) ? bp[c + 3] : 0.f;
    }
    *(float4*)(&Bs[bk][bn]) = bv;
    __syncthreads();

#pragma unroll
    for (int kk = 0; kk < 8; ++kk) {
      float a[8], b[8];
#pragma unroll
      for (int i = 0; i < 8; ++i) a[i] = As[kk][ty * 8 + i];
#pragma unroll
      for (int j = 0; j < 8; ++j) b[j] = Bs[kk][tx * 8 + j];
#pragma unroll
      for (int i = 0; i < 8; ++i)
#pragma unroll
        for (int j = 0; j < 8; ++j) acc[i][j] = fmaf(a[i], b[j], acc[i][j]);
    }
    __syncthreads();
  }

#pragma unroll
  for (int i = 0; i < 8; ++i) {
    int r = row0 + ty * 8 + i;
    if (r >= M) continue;
#pragma unroll
    for (int j = 0; j < 8; ++j) {
      int c = col0 + tx * 8 + j;
      if (c >= N) continue;
      float v = acc[i][j];
      if (bias)  v += bias[c];
      if (ep == 1) v = 0.5f * v * (1.0f + erff(v * 0.70710678118654752f));
      if (resid) v += resid[(size_t)r * N + c];
      C[(size_t)r * N + c] = v;
    }
  }
}

// ---------------- streaming attention: one wave per (b,h,i) ----------------
// qkv row layout: [q(768) | k(768) | v(768)], head h occupies cols h*64..h*64+63
// softmax variant: numer = exp(s*scale); out = numer@V / (sum(numer) + 1e-8)
__global__ __launch_bounds__(64) void attn_stream(const float* __restrict__ qkv,
                                                  float* __restrict__ out) {
  int idx = blockIdx.x;
  int i  = idx % NTOK;
  int bh = idx / NTOK;
  int h  = bh % NH;
  int b  = bh / NH;
  int d  = threadIdx.x;                 // 0..63
  const float scale = 0.125f;           // 64^-0.5

  const float* base = qkv + (size_t)b * NTOK * 2304;
  float qd = base[(size_t)i * 2304 + h * 64 + d] * scale;

  float sum = 0.f, acc = 0.f;
  for (int j = 0; j < NTOK; ++j) {
    const float* kj = base + (size_t)j * 2304 + 768 + h * 64;
    float p = qd * kj[d];
#pragma unroll
    for (int off = 32; off; off >>= 1) p += __shfl_xor(p, off);
    float e = __expf(p);
    sum += e;
    acc += e * kj[768 + d];             // v is 768 floats after k
  }
  out[((size_t)b * NTOK + i) * 768 + h * 64 + d] = acc / (sum + 1e-8f);
}

// ---------------- host launch ----------------
extern "C" void kernel_launch(void* const* d_in, const int* in_sizes, int n_in,
                              void* d_out, int out_size, void* d_ws, size_t ws_size,
                              hipStream_t stream) {
  const float* img       = (const float*)d_in[0];
  const float* p_ln1_g   = (const float*)d_in[1];
  const float* p_ln1_b   = (const float*)d_in[2];
  const float* patch_w   = (const float*)d_in[3];
  const float* patch_b   = (const float*)d_in[4];
  const float* p_ln2_g   = (const float*)d_in[5];
  const float* p_ln2_b   = (const float*)d_in[6];
  const float* pos_emb   = (const float*)d_in[7];
  const float* cls_tok   = (const float*)d_in[8];
  const float* attn_ln_g = (const float*)d_in[9];
  const float* attn_ln_b = (const float*)d_in[10];
  const float* w_qkv     = (const float*)d_in[11];
  const float* w_out     = (const float*)d_in[12];
  const float* b_out     = (const float*)d_in[13];
  const float* ff_ln_g   = (const float*)d_in[14];
  const float* ff_ln_b   = (const float*)d_in[15];
  const float* ff_w1     = (const float*)d_in[16];
  const float* ff_b1     = (const float*)d_in[17];
  const float* ff_w2     = (const float*)d_in[18];
  const float* ff_b2     = (const float*)d_in[19];
  const float* fin_ln_g  = (const float*)d_in[20];
  const float* fin_ln_b  = (const float*)d_in[21];
  const float* head_w    = (const float*)d_in[22];
  const float* head_b    = (const float*)d_in[23];
  float* out = (float*)d_out;

  // workspace carve (floats). buf region is reused: [qkv | attn_out] during attention,
  // [hid] during FF (ROWS*2304 + ROWS*768 == ROWS*3072). Total = ROWS*(768*2+3072+768)*4B ≈ 232 MB.
  float* ws   = (float*)d_ws;
  float* x    = ws;                                 // ROWS x 768
  float* xn   = x  + (size_t)ROWS * 768;            // ROWS x 768
  float* buf  = xn + (size_t)ROWS * 768;
  float* qkv  = buf;                                // ROWS x 2304
  float* aout = buf + (size_t)ROWS * 2304;          // ROWS x 768
  float* hid  = buf;                                // ROWS x 3072 (aliases qkv+aout)
  float* xp   = xn;                                 // PROWS x 768 (patch LN1 out)
  float* xe   = aout;                               // PROWS x 768 (patch GEMM out)
  float* xcls = xn;                                 // 64 x 768 (final LN out)

  dim3 blk(256);
  dim3 g_row_ep((768 + 127) / 128, (PROWS + 127) / 128);

  // ---- patch embedding ----
  patch_ln1<<<PROWS, blk, 0, stream>>>(img, p_ln1_g, p_ln1_b, xp);
  gemm128<<<g_row_ep, blk, 0, stream>>>(xp, patch_w, patch_b, nullptr, xe,
                                        PROWS, 768, 768, 0);
  ln2_pos<<<PROWS, blk, 0, stream>>>(xe, p_ln2_g, p_ln2_b, pos_emb, x);
  cls_init<<<B_, blk, 0, stream>>>(cls_tok, pos_emb, x);

  dim3 g_qkv((2304 + 127) / 128, (ROWS + 127) / 128);
  dim3 g_d  ((768  + 127) / 128, (ROWS + 127) / 128);
  dim3 g_ff ((MFF  + 127) / 128, (ROWS + 127) / 128);

  for (int l = 0; l < NL; ++l) {
    ln_rows<<<ROWS, blk, 0, stream>>>(x, 768, attn_ln_g + (size_t)l * 768,
                                      attn_ln_b + (size_t)l * 768, xn);
    gemm128<<<g_qkv, blk, 0, stream>>>(xn, w_qkv + (size_t)l * 768 * 2304,
                                       nullptr, nullptr, qkv, ROWS, 2304, 768, 0);
    attn_stream<<<B_ * NH * NTOK, dim3(64), 0, stream>>>(qkv, aout);
    gemm128<<<g_d, blk, 0, stream>>>(aout, w_out + (size_t)l * 768 * 768,
                                     b_out + (size_t)l * 768, x, x, ROWS, 768, 768, 0);
    ln_rows<<<ROWS, blk, 0, stream>>>(x, 768, ff_ln_g + (size_t)l * 768,
                                      ff_ln_b + (size_t)l * 768, xn);
    gemm128<<<g_ff, blk, 0, stream>>>(xn, ff_w1 + (size_t)l * 768 * MFF,
                                      ff_b1 + (size_t)l * MFF, nullptr, hid,
                                      ROWS, MFF, 768, 1);
    gemm128<<<g_d, blk, 0, stream>>>(hid, ff_w2 + (size_t)l * MFF * 768,
                                     ff_b2 + (size_t)l * 768, x, x, ROWS, 768, MFF, 0);
  }

  // ---- final LN on cls rows + head ----
  ln_rows<<<B_, blk, 0, stream>>>(x, (long)NTOK * 768, fin_ln_g, fin_ln_b, xcls);
  gemm128<<<dim3((NCLS + 127) / 128, 1), blk, 0, stream>>>(xcls, head_w, head_b, nullptr,
                                                           out, B_, NCLS, 768, 0);
}

// Round 2
// 6012.357 us; speedup vs baseline: 8.7040x; 8.7040x over previous
//
#include <hip/hip_runtime.h>
#include <hip/hip_bf16.h>
#include <math.h>

// ---- problem constants ----
#define B_     64
#define NTOK   197
#define NPATCH 196
#define D768   768
#define NL     12
#define NH     12
#define MFF    3072
#define NCLS   1000
#define ROWS   (B_ * NTOK)      // 12608
#define PROWS  (B_ * NPATCH)    // 12544
#define ROWS_PAD 12672          // 12608 padded to multiple of 128 + staging slack

typedef unsigned short ushort;
typedef __bf16 bf16x8 __attribute__((ext_vector_type(8)));
typedef float  f32x4  __attribute__((ext_vector_type(4)));

__device__ __forceinline__ ushort f2b(float f) {
  __hip_bfloat16 h = __float2bfloat16(f);
  return *reinterpret_cast<ushort*>(&h);
}

__device__ __forceinline__ void gload16(const ushort* g, ushort* lds) {
  __builtin_amdgcn_global_load_lds((const __attribute__((address_space(1))) void*)g,
                                   (__attribute__((address_space(3))) void*)lds, 16, 0, 0);
}

// ---------------- block-wide mean/rstd over 768 elems (256 threads) ----------------
__device__ __forceinline__ void block_mean_rstd(float s, float sq, float& mean, float& rstd) {
#pragma unroll
  for (int off = 32; off; off >>= 1) { s += __shfl_xor(s, off); sq += __shfl_xor(sq, off); }
  __shared__ float ss[4], ssq[4];
  int w = threadIdx.x >> 6;
  if ((threadIdx.x & 63) == 0) { ss[w] = s; ssq[w] = sq; }
  __syncthreads();
  s  = ss[0] + ss[1] + ss[2] + ss[3];
  sq = ssq[0] + ssq[1] + ssq[2] + ssq[3];
  mean = s * (1.0f / 768.0f);
  float var = sq * (1.0f / 768.0f) - mean * mean;
  rstd = rsqrtf(var + 1e-5f);
}

// ---------------- LN over rows of 768 (fp32 in, bf16 out) ----------------
__global__ __launch_bounds__(256) void ln_rows_b(const float* __restrict__ in, long in_stride,
                                                 const float* __restrict__ g,
                                                 const float* __restrict__ bta,
                                                 ushort* __restrict__ out) {
  const float* xr = in + (size_t)blockIdx.x * in_stride;
  int t = threadIdx.x;
  float v0 = xr[t], v1 = xr[t + 256], v2 = xr[t + 512];
  float mean, rstd;
  block_mean_rstd(v0 + v1 + v2, v0 * v0 + v1 * v1 + v2 * v2, mean, rstd);
  ushort* o = out + (size_t)blockIdx.x * 768;
  o[t]       = f2b((v0 - mean) * rstd * g[t]       + bta[t]);
  o[t + 256] = f2b((v1 - mean) * rstd * g[t + 256] + bta[t + 256]);
  o[t + 512] = f2b((v2 - mean) * rstd * g[t + 512] + bta[t + 512]);
}

// ---------------- patch extraction + LN1 (bf16 out) ----------------
__global__ __launch_bounds__(256) void patch_ln1(const float* __restrict__ img,
                                                 const float* __restrict__ g,
                                                 const float* __restrict__ bta,
                                                 ushort* __restrict__ xp) {
  int pidx = blockIdx.x;                 // b*196 + ph*14 + pw
  int b = pidx / NPATCH, hw = pidx % NPATCH;
  int ph = hw / 14, pw = hw % 14;
  int t = threadIdx.x;
  float v[3];
#pragma unroll
  for (int u = 0; u < 3; ++u) {
    int k = t + u * 256;                  // feature index (p1*16+p2)*3 + c
    int c = k % 3, p2 = (k / 3) & 15, p1 = k / 48;
    v[u] = img[(((size_t)b * 3 + c) * 224 + ph * 16 + p1) * 224 + pw * 16 + p2];
  }
  float mean, rstd;
  block_mean_rstd(v[0] + v[1] + v[2], v[0] * v[0] + v[1] * v[1] + v[2] * v[2], mean, rstd);
  ushort* o = xp + (size_t)pidx * 768;
#pragma unroll
  for (int u = 0; u < 3; ++u) { int k = t + u * 256; o[k] = f2b((v[u] - mean) * rstd * g[k] + bta[k]); }
}

// ---------------- LN2 + pos_emb, scatter into x at token 1+i (fp32) ----------------
__global__ __launch_bounds__(256) void ln2_pos(const float* __restrict__ xe,
                                               const float* __restrict__ g,
                                               const float* __restrict__ bta,
                                               const float* __restrict__ pos,
                                               float* __restrict__ x) {
  int pidx = blockIdx.x;
  int b = pidx / NPATCH, i = pidx % NPATCH;
  const float* xr = xe + (size_t)pidx * 768;
  int t = threadIdx.x;
  float v0 = xr[t], v1 = xr[t + 256], v2 = xr[t + 512];
  float mean, rstd;
  block_mean_rstd(v0 + v1 + v2, v0 * v0 + v1 * v1 + v2 * v2, mean, rstd);
  const float* p = pos + (size_t)(1 + i) * 768;
  float* o = x + ((size_t)b * NTOK + 1 + i) * 768;
  o[t]       = (v0 - mean) * rstd * g[t]       + bta[t]       + p[t];
  o[t + 256] = (v1 - mean) * rstd * g[t + 256] + bta[t + 256] + p[t + 256];
  o[t + 512] = (v2 - mean) * rstd * g[t + 512] + bta[t + 512] + p[t + 512];
}

// ---------------- cls token + pos_emb[0] ----------------
__global__ __launch_bounds__(256) void cls_init(const float* __restrict__ cls_tok,
                                                const float* __restrict__ pos,
                                                float* __restrict__ x) {
  int b = blockIdx.x, t = threadIdx.x;
  float* o = x + (size_t)b * NTOK * 768;
#pragma unroll
  for (int u = 0; u < 3; ++u) { int k = t + u * 256; o[k] = cls_tok[k] + pos[k]; }
}

// ---------------- cast + transpose: W fp32 [K][N] -> Wt bf16 [N][K] ----------------
__global__ __launch_bounds__(256) void transpose_cast(const float* __restrict__ W,
                                                      ushort* __restrict__ Wt,
                                                      int K, int N) {
  __shared__ float t[32][33];
  int n0 = blockIdx.x * 32, k0 = blockIdx.y * 32;
  int tx = threadIdx.x, ty = threadIdx.y;   // 32 x 8
#pragma unroll
  for (int u = 0; u < 32; u += 8) {
    int n = n0 + tx;
    t[ty + u][tx] = (n < N) ? W[(size_t)(k0 + ty + u) * N + n] : 0.f;
  }
  __syncthreads();
#pragma unroll
  for (int u = 0; u < 32; u += 8) {
    int n = n0 + ty + u;
    if (n < N) Wt[(size_t)n * K + k0 + tx] = f2b(t[tx][ty + u]);
  }
}

// ---------------- bf16 MFMA GEMM: C = A @ Bt^T ----------------
// A [M][K] bf16 row-major, Bt [N][K] bf16 row-major. K % 32 == 0.
// 128x128 tile, BK=32, 256 thr (4 waves, 2x2), each wave 64x64 = 4x4 frags of 16x16.
// EP: 0 none, 1 exact GELU. RESID: add fp32 resid. OBF: 1 -> bf16 out, 0 -> fp32 out.
template<int EP, int RESID, int OBF>
__global__ __launch_bounds__(256) void gemm_bt(const ushort* __restrict__ A,
                                               const ushort* __restrict__ Bt,
                                               const float* __restrict__ bias,
                                               const float* __restrict__ resid,
                                               void* __restrict__ C,
                                               int M, int N, int K) {
  __shared__ ushort As[128 * 32];
  __shared__ ushort Bs[128 * 32];
  int tid = threadIdx.x;
  int w = tid >> 6, l = tid & 63;
  int fr = l & 15, fc = l >> 4;
  int row0 = blockIdx.y * 128, col0 = blockIdx.x * 128;
  int wr = (w >> 1) * 64, wc = (w & 1) * 64;

  // staging coords: wave w stages rows w*32..w*32+31 of both tiles (two 16-row chunks)
  int srow0 = w * 32 + (l >> 2);
  int srow1 = srow0 + 16;
  int sc0 = (((l & 3) ^ ((srow0 >> 1) & 3)) << 3);   // swizzled source chunk col (elems)
  int sc1 = (((l & 3) ^ ((srow1 >> 1) & 3)) << 3);
  const ushort* ga0 = A  + (size_t)(row0 + srow0) * K + sc0;
  const ushort* ga1 = A  + (size_t)(row0 + srow1) * K + sc1;
  const ushort* gb0 = Bt + (size_t)(col0 + srow0) * K + sc0;
  const ushort* gb1 = Bt + (size_t)(col0 + srow1) * K + sc1;

  // frag read indices (ushort elems within tile), constant over K loop
  int idxA[4], idxB[4];
#pragma unroll
  for (int m = 0; m < 4; ++m) {
    int r = wr + m * 16 + fr;
    idxA[m] = r * 32 + ((fc ^ ((r >> 1) & 3)) << 3);
  }
#pragma unroll
  for (int n = 0; n < 4; ++n) {
    int r = wc + n * 16 + fr;
    idxB[n] = r * 32 + ((fc ^ ((r >> 1) & 3)) << 3);
  }

  f32x4 acc[4][4] = {};

  for (int k0 = 0; k0 < K; k0 += 32) {
    gload16(ga0 + k0, &As[w * 1024]);
    gload16(ga1 + k0, &As[w * 1024 + 512]);
    gload16(gb0 + k0, &Bs[w * 1024]);
    gload16(gb1 + k0, &Bs[w * 1024 + 512]);
    __syncthreads();
    bf16x8 af[4], bf[4];
#pragma unroll
    for (int m = 0; m < 4; ++m) af[m] = *(const bf16x8*)(As + idxA[m]);
#pragma unroll
    for (int n = 0; n < 4; ++n) bf[n] = *(const bf16x8*)(Bs + idxB[n]);
#pragma unroll
    for (int m = 0; m < 4; ++m)
#pragma unroll
      for (int n = 0; n < 4; ++n)
        acc[m][n] = __builtin_amdgcn_mfma_f32_16x16x32_bf16(af[m], bf[n], acc[m][n], 0, 0, 0);
    __syncthreads();
  }

  // epilogue: C row = row0+wr+m*16+fc*4+r, col = col0+wc+n*16+fr
#pragma unroll
  for (int n = 0; n < 4; ++n) {
    int col = col0 + wc + n * 16 + fr;
    if (col >= N) continue;
    float bv = bias ? bias[col] : 0.f;
#pragma unroll
    for (int m = 0; m < 4; ++m) {
#pragma unroll
      for (int r = 0; r < 4; ++r) {
        int row = row0 + wr + m * 16 + fc * 4 + r;
        if (row >= M) continue;
        float v = acc[m][n][r] + bv;
        if (EP == 1) v = 0.5f * v * (1.0f + erff(v * 0.70710678118654752f));
        if (RESID) v += resid[(size_t)row * N + col];
        if (OBF) ((ushort*)C)[(size_t)row * N + col] = f2b(v);
        else     ((float*)C)[(size_t)row * N + col]  = v;
      }
    }
  }
}

// ---------------- MFMA flash attention ----------------
// qkv bf16 [ROWS_PAD][2304] rows = [q(768)|k(768)|v(768)]; head h at cols h*64.
// block = (b, h, qt): 4 waves, wave w owns q rows qt*64 + w*16 .. +15.
// softmax: e = exp(s*scale); out = (e @ V) / (sum(e) + 1e-8)   (no max subtract)
__global__ __launch_bounds__(256) void attn_mfma(const ushort* __restrict__ qkv,
                                                 ushort* __restrict__ aout) {
  int bid = blockIdx.x;
  int qt = bid & 3;
  int h  = (bid >> 2) % NH;
  int b  = (bid >> 2) / NH;
  int tid = threadIdx.x, w = tid >> 6, l = tid & 63;
  int fr = l & 15, fc = l >> 4;

  __shared__ ushort Vt[64 * 64];        // swizzled V^T tile [d][key]
  __shared__ ushort Pl[4 * 16 * 64];    // per-wave P [qrow][key], swizzled

  const size_t brow = (size_t)b * NTOK;
  int q0 = qt * 64 + w * 16;

  bf16x8 qf[2];
  {
    const ushort* qp = qkv + (brow + q0 + fr) * 2304 + h * 64 + fc * 8;
    qf[0] = *(const bf16x8*)qp;
    qf[1] = *(const bf16x8*)(qp + 32);
  }
  float rs[4] = {0.f, 0.f, 0.f, 0.f};
  f32x4 oc[4] = {};

  for (int kt = 0; kt < 4; ++kt) {
    __syncthreads();   // previous tile's Vt reads complete
    // stage V^T tile (zero-filled beyond 197 keys)
    {
      int key = tid >> 2, d0 = (tid & 3) * 16;
      int j = kt * 64 + key;
      bool valid = j < NTOK;
      const ushort* vp = qkv + (brow + j) * 2304 + 1536 + h * 64 + d0;
      ushort vbuf[16];
      if (valid) {
        *(bf16x8*)(vbuf)     = *(const bf16x8*)vp;
        *(bf16x8*)(vbuf + 8) = *(const bf16x8*)(vp + 8);
      } else {
#pragma unroll
        for (int i = 0; i < 16; ++i) vbuf[i] = 0;
      }
#pragma unroll
      for (int i = 0; i < 16; ++i) {
        int d = d0 + i;
        int byte = d * 128 + ((((key >> 3)) ^ (d & 7)) << 4) + (key & 7) * 2;
        Vt[byte >> 1] = vbuf[i];
      }
    }
    // S = Q K^T   (16 q-rows x 64 keys per wave)
    f32x4 sc[4];
#pragma unroll
    for (int n = 0; n < 4; ++n) {
      f32x4 z = {};
      const ushort* kp = qkv + (brow + kt * 64 + n * 16 + fr) * 2304 + 768 + h * 64 + fc * 8;
      bf16x8 k0 = *(const bf16x8*)kp;
      bf16x8 k1 = *(const bf16x8*)(kp + 32);
      z = __builtin_amdgcn_mfma_f32_16x16x32_bf16(qf[0], k0, z, 0, 0, 0);
      z = __builtin_amdgcn_mfma_f32_16x16x32_bf16(qf[1], k1, z, 0, 0, 0);
      sc[n] = z;
    }
    // exp + mask + rowsum + P -> LDS (bf16, swizzled)
    float part[4] = {0.f, 0.f, 0.f, 0.f};
#pragma unroll
    for (int n = 0; n < 4; ++n) {
      int j = kt * 64 + n * 16 + fr;
      bool jv = j < NTOK;
#pragma unroll
      for (int r = 0; r < 4; ++r) {
        float e = jv ? __expf(sc[n][r] * 0.125f) : 0.f;
        part[r] += e;
        int row = fc * 4 + r, col = n * 16 + fr;
        int byte = row * 128 + (((col >> 3) ^ (row & 7)) << 4) + (col & 7) * 2;
        Pl[w * 1024 + (byte >> 1)] = f2b(e);
      }
    }
#pragma unroll
    for (int r = 0; r < 4; ++r) {
      float p = part[r];
      p += __shfl_xor(p, 1); p += __shfl_xor(p, 2);
      p += __shfl_xor(p, 4); p += __shfl_xor(p, 8);
      rs[r] += p;
    }
    __syncthreads();   // Vt + P visible
    // O += P @ V
#pragma unroll
    for (int ks = 0; ks < 2; ++ks) {
      int prow = fr;
      int pbyte = prow * 128 + (((ks * 4 + fc) ^ (prow & 7)) << 4);
      bf16x8 pf = *(const bf16x8*)(Pl + w * 1024 + (pbyte >> 1));
#pragma unroll
      for (int n = 0; n < 4; ++n) {
        int d = n * 16 + fr;
        int vb = d * 128 + (((ks * 4 + fc) ^ (d & 7)) << 4);
        bf16x8 vf = *(const bf16x8*)(Vt + (vb >> 1));
        oc[n] = __builtin_amdgcn_mfma_f32_16x16x32_bf16(pf, vf, oc[n], 0, 0, 0);
      }
    }
  }
  // epilogue: divide by rowsum, store bf16
#pragma unroll
  for (int n = 0; n < 4; ++n) {
#pragma unroll
    for (int r = 0; r < 4; ++r) {
      int q = q0 + fc * 4 + r;
      if (q < NTOK) {
        float v = oc[n][r] / (rs[r] + 1e-8f);
        aout[(brow + q) * 768 + h * 64 + n * 16 + fr] = f2b(v);
      }
    }
  }
}

// ---------------- host launch ----------------
extern "C" void kernel_launch(void* const* d_in, const int* in_sizes, int n_in,
                              void* d_out, int out_size, void* d_ws, size_t ws_size,
                              hipStream_t stream) {
  const float* img       = (const float*)d_in[0];
  const float* p_ln1_g   = (const float*)d_in[1];
  const float* p_ln1_b   = (const float*)d_in[2];
  const float* patch_w   = (const float*)d_in[3];
  const float* patch_b   = (const float*)d_in[4];
  const float* p_ln2_g   = (const float*)d_in[5];
  const float* p_ln2_b   = (const float*)d_in[6];
  const float* pos_emb   = (const float*)d_in[7];
  const float* cls_tok   = (const float*)d_in[8];
  const float* attn_ln_g = (const float*)d_in[9];
  const float* attn_ln_b = (const float*)d_in[10];
  const float* w_qkv     = (const float*)d_in[11];
  const float* w_out     = (const float*)d_in[12];
  const float* b_out     = (const float*)d_in[13];
  const float* ff_ln_g   = (const float*)d_in[14];
  const float* ff_ln_b   = (const float*)d_in[15];
  const float* ff_w1     = (const float*)d_in[16];
  const float* ff_b1     = (const float*)d_in[17];
  const float* ff_w2     = (const float*)d_in[18];
  const float* ff_b2     = (const float*)d_in[19];
  const float* fin_ln_g  = (const float*)d_in[20];
  const float* fin_ln_b  = (const float*)d_in[21];
  const float* head_w    = (const float*)d_in[22];
  const float* head_b    = (const float*)d_in[23];
  float* out = (float*)d_out;

  // ---- workspace carve ----
  char* p = (char*)d_ws;
  auto alloc = [&](size_t bytes) { char* r = p; p += (bytes + 255) & ~(size_t)255; return r; };
  float*  x      = (float*) alloc((size_t)ROWS_PAD * 768 * 4);
  ushort* xnb    = (ushort*)alloc((size_t)ROWS_PAD * 768 * 2);
  ushort* qkvb   = (ushort*)alloc((size_t)ROWS_PAD * 2304 * 2);
  ushort* aoutb  = (ushort*)alloc((size_t)ROWS_PAD * 768 * 2);
  ushort* wtq    = (ushort*)alloc((size_t)2304 * 768 * 2);
  ushort* wto    = (ushort*)alloc((size_t)768 * 768 * 2);
  ushort* wt1    = (ushort*)alloc((size_t)3072 * 768 * 2);
  ushort* wt2    = (ushort*)alloc((size_t)768 * 3072 * 2);
  ushort* pwt    = (ushort*)alloc((size_t)768 * 768 * 2);
  ushort* hwt    = (ushort*)alloc((size_t)1024 * 768 * 2);
  ushort* xclsb  = (ushort*)alloc((size_t)128 * 768 * 2);
  ushort* hidb   = qkvb;                 // [ROWS_PAD][3072] aliases qkvb+aoutb
  ushort* xpb    = xnb;                  // patch LN1 out (12544 rows)
  float*  xe     = (float*)qkvb;         // patch GEMM out fp32 (pre-loop only)

  dim3 blk(256), tblk(32, 8);

  // ---- patch embedding ----
  transpose_cast<<<dim3(24, 24), tblk, 0, stream>>>(patch_w, pwt, 768, 768);
  transpose_cast<<<dim3(32, 24), tblk, 0, stream>>>(head_w, hwt, 768, 1000);
  patch_ln1<<<PROWS, blk, 0, stream>>>(img, p_ln1_g, p_ln1_b, xpb);
  gemm_bt<0, 0, 0><<<dim3(6, 98), blk, 0, stream>>>(xpb, pwt, patch_b, nullptr, xe,
                                                    PROWS, 768, 768);
  ln2_pos<<<PROWS, blk, 0, stream>>>(xe, p_ln2_g, p_ln2_b, pos_emb, x);
  cls_init<<<B_, blk, 0, stream>>>(cls_tok, pos_emb, x);

  for (int l = 0; l < NL; ++l) {
    transpose_cast<<<dim3(72, 24), tblk, 0, stream>>>(w_qkv + (size_t)l * 768 * 2304, wtq, 768, 2304);
    transpose_cast<<<dim3(24, 24), tblk, 0, stream>>>(w_out + (size_t)l * 768 * 768,  wto, 768, 768);
    transpose_cast<<<dim3(96, 24), tblk, 0, stream>>>(ff_w1 + (size_t)l * 768 * MFF,  wt1, 768, MFF);
    transpose_cast<<<dim3(24, 96), tblk, 0, stream>>>(ff_w2 + (size_t)l * MFF * 768,  wt2, MFF, 768);

    ln_rows_b<<<ROWS, blk, 0, stream>>>(x, 768, attn_ln_g + (size_t)l * 768,
                                        attn_ln_b + (size_t)l * 768, xnb);
    gemm_bt<0, 0, 1><<<dim3(18, 99), blk, 0, stream>>>(xnb, wtq, nullptr, nullptr, qkvb,
                                                       ROWS, 2304, 768);
    attn_mfma<<<B_ * NH * 4, blk, 0, stream>>>(qkvb, aoutb);
    gemm_bt<0, 1, 0><<<dim3(6, 99), blk, 0, stream>>>(aoutb, wto, b_out + (size_t)l * 768,
                                                      x, x, ROWS, 768, 768);
    ln_rows_b<<<ROWS, blk, 0, stream>>>(x, 768, ff_ln_g + (size_t)l * 768,
                                        ff_ln_b + (size_t)l * 768, xnb);
    gemm_bt<1, 0, 1><<<dim3(24, 99), blk, 0, stream>>>(xnb, wt1, ff_b1 + (size_t)l * MFF,
                                                       nullptr, hidb, ROWS, MFF, 768);
    gemm_bt<0, 1, 0><<<dim3(6, 99), blk, 0, stream>>>(hidb, wt2, ff_b2 + (size_t)l * 768,
                                                      x, x, ROWS, 768, MFF);
  }

  // ---- final LN (cls rows) + head ----
  ln_rows_b<<<B_, blk, 0, stream>>>(x, (long)NTOK * 768, fin_ln_g, fin_ln_b, xclsb);
  gemm_bt<0, 0, 0><<<dim3(8, 1), blk, 0, stream>>>(xclsb, hwt, head_b, nullptr, out,
                                                   B_, NCLS, 768);
}